// Round 1
// baseline (292.289 us; speedup 1.0000x reference)
//
#include <hip/hip_runtime.h>

// mIoU over int32 class maps, NUM=21 classes (values 0..21; class 0 excluded
// from iou). Outputs: out[0]=mIoU, out[1..21]=iou[c] for classes 1..21 (f32).
//
// Structure: zero 66 global counters -> replicated-LDS histogram kernel
// (int4 loads, 32 LDS replicas per block to cut same-address atomic
// serialization) -> 1-wave finalize.

#define NUMC   21
#define NBINS  22           // classes 0..21
#define NCNT   (3 * NBINS)  // [0..21]=cnt_true, [22..43]=cnt_pred, [44..65]=inter
#define REPS   32           // one replica per 8 lanes; 256 threads -> 32 replicas
#define RSTRIDE 67          // odd stride: spreads replicas across banks

__global__ void zero_counters(unsigned int* __restrict__ g) {
    int i = threadIdx.x;
    if (i < NCNT) g[i] = 0u;
}

__global__ void __launch_bounds__(256) hist_kernel(
        const int* __restrict__ yp, const int* __restrict__ yt,
        unsigned int* __restrict__ g, int n) {
    __shared__ unsigned int h[REPS * RSTRIDE];
    for (int i = threadIdx.x; i < REPS * RSTRIDE; i += blockDim.x) h[i] = 0u;
    __syncthreads();

    unsigned int* hh = h + (threadIdx.x >> 3) * RSTRIDE; // replica per 8 lanes

    const int n4 = n >> 2;
    const int4* __restrict__ yp4 = (const int4*)yp;
    const int4* __restrict__ yt4 = (const int4*)yt;
    int tid = blockIdx.x * blockDim.x + threadIdx.x;
    int stride = gridDim.x * blockDim.x;

    for (int i = tid; i < n4; i += stride) {
        int4 p = yp4[i];
        int4 t = yt4[i];
#define PROC(P, T)                                        \
        do {                                              \
            atomicAdd(&hh[(T)], 1u);                      \
            atomicAdd(&hh[NBINS + (P)], 1u);              \
            if ((P) == (T)) atomicAdd(&hh[2*NBINS + (T)], 1u); \
        } while (0)
        PROC(p.x, t.x);
        PROC(p.y, t.y);
        PROC(p.z, t.z);
        PROC(p.w, t.w);
#undef PROC
    }

    // tail (n not multiple of 4) — handled by one thread, straight to global
    if (tid == 0) {
        for (int i = n4 << 2; i < n; i++) {
            int p = yp[i], t = yt[i];
            atomicAdd(&g[t], 1u);
            atomicAdd(&g[NBINS + p], 1u);
            if (p == t) atomicAdd(&g[2*NBINS + t], 1u);
        }
    }

    __syncthreads();
    // block reduction: 66 counters, sum 32 replicas each, one global atomic per counter
    for (int i = threadIdx.x; i < NCNT; i += blockDim.x) {
        unsigned int s = 0;
        #pragma unroll
        for (int r = 0; r < REPS; r++) s += h[r * RSTRIDE + i];
        atomicAdd(&g[i], s);
    }
}

__global__ void finalize_kernel(const unsigned int* __restrict__ g,
                                float* __restrict__ out) {
    int lane = threadIdx.x; // 64 threads, single wave
    float iou = 0.0f, pres = 0.0f;
    if (lane < NUMC) {
        int c = lane + 1; // classes 1..21
        float ct = (float)g[c];
        float cp = (float)g[NBINS + c];
        float ci = (float)g[2 * NBINS + c];
        float uni = ct + cp - ci;
        iou = (ci + 1e-6f) / (uni + 1e-6f);
        pres = (ct > 0.0f) ? 1.0f : 0.0f;
        out[1 + lane] = iou;
    }
    float v = iou * pres;
    float p = pres;
    #pragma unroll
    for (int off = 32; off > 0; off >>= 1) {
        v += __shfl_down(v, off);
        p += __shfl_down(p, off);
    }
    if (lane == 0) out[0] = v / fmaxf(p, 1.0f);
}

extern "C" void kernel_launch(void* const* d_in, const int* in_sizes, int n_in,
                              void* d_out, int out_size, void* d_ws, size_t ws_size,
                              hipStream_t stream) {
    const int* yp = (const int*)d_in[0];
    const int* yt = (const int*)d_in[1];
    int n = in_sizes[0];
    unsigned int* g = (unsigned int*)d_ws; // 66 uints
    float* out = (float*)d_out;

    zero_counters<<<1, 128, 0, stream>>>(g);
    hist_kernel<<<2048, 256, 0, stream>>>(yp, yt, g, n);
    finalize_kernel<<<1, 64, 0, stream>>>(g, out);
}

// Round 2
// 285.197 us; speedup vs baseline: 1.0249x; 1.0249x over previous
//
#include <hip/hip_runtime.h>

// mIoU over int32 class maps, NUM=21 (values 0..21; class 0 excluded from iou).
// out[0]=mIoU, out[1..21]=iou for classes 1..21 (f32).
//
// R2 design: JOINT 22x22 histogram H[t][p] -> one ds_add per element (was 3).
// cnt_true/cnt_pred/inter are marginals of H, computed in the finalize wave.
// Per-wave LDS replicas (stride 485) -> per-block partial rows in d_ws
// (coalesced, non-atomic) -> 484-block reduce -> 1-wave finalize.
// NOTE: random class data => few same-address DS collisions over 484 bins.

#define NUMC  21
#define NBINS 22
#define JBINS (NBINS * NBINS)   // 484
#define RSTR  485               // odd replica stride: spreads banks
#define NREP  4                 // one replica per wave (256 threads)

__global__ void __launch_bounds__(256) hist_joint(
        const int* __restrict__ yp, const int* __restrict__ yt,
        unsigned int* __restrict__ partials, int n, int nblocks) {
    __shared__ unsigned int h[NREP * RSTR];
    for (int i = threadIdx.x; i < NREP * RSTR; i += 256) h[i] = 0u;
    __syncthreads();

    unsigned int* hh = h + (threadIdx.x >> 6) * RSTR;  // replica per wave

    const int4* __restrict__ yp4 = (const int4*)yp;
    const int4* __restrict__ yt4 = (const int4*)yt;
    const int n4 = n >> 2;
    int tid = blockIdx.x * 256 + threadIdx.x;
    int stride = nblocks * 256;

    for (int i = tid; i < n4; i += stride) {
        int4 p = yp4[i];
        int4 t = yt4[i];
        atomicAdd(&hh[t.x * NBINS + p.x], 1u);
        atomicAdd(&hh[t.y * NBINS + p.y], 1u);
        atomicAdd(&hh[t.z * NBINS + p.z], 1u);
        atomicAdd(&hh[t.w * NBINS + p.w], 1u);
    }

    // tail (n % 4 != 0): one thread, into its own replica (block 0, wave 0)
    if (tid == 0) {
        for (int i = n4 << 2; i < n; i++)
            atomicAdd(&hh[yt[i] * NBINS + yp[i]], 1u);
    }

    __syncthreads();
    // sum the 4 replicas, write this block's partial row (coalesced, no atomics)
    for (int c = threadIdx.x; c < JBINS; c += 256) {
        unsigned int s = 0;
        #pragma unroll
        for (int r = 0; r < NREP; r++) s += h[r * RSTR + c];
        partials[(size_t)blockIdx.x * JBINS + c] = s;
    }
}

__global__ void __launch_bounds__(256) reduce_partials(
        const unsigned int* __restrict__ partials,
        unsigned int* __restrict__ g, int nblocks) {
    __shared__ unsigned int lds[256];
    const int c = blockIdx.x;  // one block per joint bin
    unsigned int s = 0;
    for (int b = threadIdx.x; b < nblocks; b += 256)
        s += partials[(size_t)b * JBINS + c];
    lds[threadIdx.x] = s;
    __syncthreads();
    for (int w = 128; w > 0; w >>= 1) {
        if (threadIdx.x < w) lds[threadIdx.x] += lds[threadIdx.x + w];
        __syncthreads();
    }
    if (threadIdx.x == 0) g[c] = lds[0];
}

__global__ void finalize_kernel(const unsigned int* __restrict__ g,
                                float* __restrict__ out) {
    int lane = threadIdx.x;  // single wave of 64
    float iou = 0.0f, pres = 0.0f;
    if (lane >= 1 && lane <= NUMC) {
        unsigned int ct = 0, cp = 0;
        #pragma unroll
        for (int k = 0; k < NBINS; k++) {
            ct += g[lane * NBINS + k];   // row sum: cnt_true[lane]
            cp += g[k * NBINS + lane];   // col sum: cnt_pred[lane]
        }
        unsigned int ci = g[lane * NBINS + lane];
        float u = (float)ct + (float)cp - (float)ci;
        iou = ((float)ci + 1e-6f) / (u + 1e-6f);
        pres = (ct > 0u) ? 1.0f : 0.0f;
        out[lane] = iou;  // out[1..21]
    }
    float v = iou * pres, pc = pres;
    #pragma unroll
    for (int off = 32; off > 0; off >>= 1) {
        v += __shfl_down(v, off);
        pc += __shfl_down(pc, off);
    }
    if (lane == 0) out[0] = v / fmaxf(pc, 1.0f);
}

extern "C" void kernel_launch(void* const* d_in, const int* in_sizes, int n_in,
                              void* d_out, int out_size, void* d_ws, size_t ws_size,
                              hipStream_t stream) {
    const int* yp = (const int*)d_in[0];
    const int* yt = (const int*)d_in[1];
    int n = in_sizes[0];
    float* out = (float*)d_out;

    // ws layout: g[484] | partials[nb * 484]
    int nb = 2048;
    while (nb > 1 && (size_t)JBINS * 4 * ((size_t)nb + 1) > ws_size) nb >>= 1;
    unsigned int* g = (unsigned int*)d_ws;
    unsigned int* partials = g + JBINS;

    hist_joint<<<nb, 256, 0, stream>>>(yp, yt, partials, n, nb);
    reduce_partials<<<JBINS, 256, 0, stream>>>(partials, g, nb);
    finalize_kernel<<<1, 64, 0, stream>>>(g, out);
}